// Round 6
// baseline (308.863 us; speedup 1.0000x reference)
//
#include <hip/hip_runtime.h>
#include <float.h>

// Sparsemax per row, one block (256T) per row, input read EXACTLY once,
// row parked in LDS as f16 (error <=0.002 << 2e-2 threshold), ONE barrier.
// R1/R4/R5 lesson: 32 f32/thread can't live across the tau phase (remat /
// cache-thrash / scratch spill). So: candidates are gathered from registers
// BEFORE the barrier using a per-wave threshold (wave_max-1, conservative
// superset of block_max-1); Newton filters the extras naturally.

constexpr int D       = 8192;
constexpr int THREADS = 256;
constexpr int NV      = 8;      // float4 per thread
constexpr int WCAP    = 64;     // per-wave candidate capacity

typedef float    f32x4 __attribute__((ext_vector_type(4)));
typedef _Float16 f16x4 __attribute__((ext_vector_type(4)));

__global__ __launch_bounds__(THREADS, 8)   // target VGPR<=64 -> 8 blocks/CU
void sparsemax_kernel(const float* __restrict__ x, float* __restrict__ out,
                      int rows) {
    __shared__ f16x4 hrow4[D / 4];          // 16 KiB: row as f16, own-slot use
    __shared__ float cands[4][WCAP];        // 1 KiB
    __shared__ float redm[4];
    __shared__ int   ncnt[4];

    const int tid  = threadIdx.x;
    const int wave = tid >> 6, lane = tid & 63;
    const long long row = blockIdx.x;
    if (row >= rows) return;
    const f32x4* __restrict__ xr4 = reinterpret_cast<const f32x4*>(x + row * D);
    f32x4* __restrict__       or4 = reinterpret_cast<f32x4*>(out + row * D);

    // ---- single HBM read; f16 copy to LDS; thread-local max ----
    f32x4 t[NV];
    #pragma unroll
    for (int i = 0; i < NV; ++i) t[i] = xr4[tid + i * THREADS];
    float m = -FLT_MAX;
    #pragma unroll
    for (int i = 0; i < NV; ++i) {
        hrow4[tid + i * THREADS] = __builtin_convertvector(t[i], f16x4); // RTN
        m = fmaxf(m, fmaxf(fmaxf(t[i].x, t[i].y), fmaxf(t[i].z, t[i].w)));
    }

    // ---- wave-local max (shuffles) -> conservative gather threshold ----
    #pragma unroll
    for (int off = 1; off < 64; off <<= 1)
        m = fmaxf(m, __shfl_xor(m, off, 64));
    const float wthr = m - 1.0f;   // wave_max-1 <= block_max-1 <= tau

    // ---- ballot-compact candidates from LIVE registers (pre-barrier) ----
    const unsigned long long lmask = (1ull << lane) - 1ull;
    int n = 0;
    #pragma unroll
    for (int i = 0; i < NV; ++i) {
        #pragma unroll
        for (int j = 0; j < 4; ++j) {
            float v = t[i][j];
            unsigned long long mk = __ballot(v > wthr);
            if (v > wthr) {
                int pos = n + __popcll(mk & lmask);
                if (pos < WCAP) cands[wave][pos] = v;
            }
            n += __popcll(mk);
        }
    }
    if (lane == 0) { redm[wave] = m; ncnt[wave] = n; }

    __syncthreads();               // the ONLY barrier

    // ---- block max; per-wave independent Newton (shuffle-only) ----
    const float bm = fmaxf(fmaxf(redm[0], redm[1]), fmaxf(redm[2], redm[3]));
    const int n0 = ncnt[0], n1 = ncnt[1], n2 = ncnt[2], n3 = ncnt[3];
    float tau = bm - 1.0f;         // f(tau0) >= 0; Newton ascends, exact finish
    float kprev = -1.0f;

    if ((n0 | n1 | n2 | n3) <= WCAP ? (n0 <= WCAP && n1 <= WCAP && n2 <= WCAP && n3 <= WCAP) : false) {
        const float c0 = (lane < n0) ? cands[0][lane] : -FLT_MAX;
        const float c1 = (lane < n1) ? cands[1][lane] : -FLT_MAX;
        const float c2 = (lane < n2) ? cands[2][lane] : -FLT_MAX;
        const float c3 = (lane < n3) ? cands[3][lane] : -FLT_MAX;
        for (int it = 0; it < 64; ++it) {          // wave-uniform trip count
            float S = 0.f, K = 0.f;
            if (c0 > tau) { S += c0; K += 1.f; }
            if (c1 > tau) { S += c1; K += 1.f; }
            if (c2 > tau) { S += c2; K += 1.f; }
            if (c3 > tau) { S += c3; K += 1.f; }
            #pragma unroll
            for (int off = 1; off < 64; off <<= 1) {
                S += __shfl_xor(S, off, 64);
                K += __shfl_xor(K, off, 64);
            }
            tau = (S - 1.f) / K;                   // K >= 1 (max in support)
            if (K == kprev) break;                 // support fixed -> exact
            kprev = K;
        }
    } else {
        // Fallback (P ~ 0): full-row Michelot over the f16 LDS copy.
        for (int it = 0; it < 64; ++it) {
            float S = 0.f, K = 0.f;
            for (int i = 0; i < 32; ++i) {
                f16x4 hv = hrow4[lane + i * 64];
                #pragma unroll
                for (int j = 0; j < 4; ++j) {
                    float v = (float)hv[j];
                    if (v > tau) { S += v; K += 1.f; }
                }
            }
            #pragma unroll
            for (int off = 1; off < 64; off <<= 1) {
                S += __shfl_xor(S, off, 64);
                K += __shfl_xor(K, off, 64);
            }
            tau = (S - 1.f) / K;
            if (K == kprev) break;
            kprev = K;
        }
    }

    // ---- output from own f16 LDS slots; nontemporal f32x4 stores ----
    #pragma unroll
    for (int i = 0; i < NV; ++i) {
        f16x4 hv = hrow4[tid + i * THREADS];
        f32x4 o;
        o.x = fmaxf((float)hv.x - tau, 0.f);
        o.y = fmaxf((float)hv.y - tau, 0.f);
        o.z = fmaxf((float)hv.z - tau, 0.f);
        o.w = fmaxf((float)hv.w - tau, 0.f);
        __builtin_nontemporal_store(o, &or4[tid + i * THREADS]);
    }
}

extern "C" void kernel_launch(void* const* d_in, const int* in_sizes, int n_in,
                              void* d_out, int out_size, void* d_ws, size_t ws_size,
                              hipStream_t stream) {
    const float* x = (const float*)d_in[0];
    float* out = (float*)d_out;
    const int rows = in_sizes[0] / D;          // 4096
    sparsemax_kernel<<<rows, THREADS, 0, stream>>>(x, out, rows);
}